// Round 8
// baseline (95.636 us; speedup 1.0000x reference)
//
#include <hip/hip_runtime.h>
#include <math.h>
#include <stdint.h>

#define BB 128
#define MM 50
#define CC 43
#define IMGF 416.0f

// block decomposition: scale0 52x52 (11 chunks/img), scale1 26x26 (3), scale2 13x13 (1)
#define NBLK0 1408
#define NBLK01 1792
#define NBLK_TOTAL 1920

#define CELLS_PER_IMG 3549   // 2704 + 676 + 169
#define SOFF1 2704
#define SOFF2 3380
#define NCELLS (BB * CELLS_PER_IMG)   // 454272

// workspace layout:
//   int      lastGT[NCELLS]
//   unsigned mlo[NCELLS]
//   unsigned mhi[NCELLS]
//   float    partials[NBLK_TOTAL*4]
//   unsigned counter
#define PART_ELEMS (NBLK_TOTAL * 4)

// bce = max(x,0) - x*t + log1p(e^-|x|), exact algebraic rewrite with fast intrinsics
__device__ __forceinline__ float bce_fast(float x, bool t) {
    float e = __expf(-fabsf(x));
    float l = __logf(1.0f + e);
    return fmaxf(x, 0.0f) - (t ? x : 0.0f) + l;
}

__device__ __forceinline__ float focal_fast(float x, bool t) {
    float xp = t ? x : -x;
    float e = __expf(-fabsf(xp));
    float d = 1.0f + e;
    float l = __logf(d);
    float bce = fmaxf(-xp, 0.0f) + l;
    float om = __builtin_amdgcn_rcpf(d);
    if (xp >= 0.0f) om *= e;      // om = 1 - pt
    return 0.25f * om * om * bce;
}

// K1: per-image GT scatter (EXACT R2 code). Block b owns image b's cells.
__global__ __launch_bounds__(256) void v3_assign(
    const float* __restrict__ bboxes, const int* __restrict__ labels,
    int* __restrict__ lastGT, unsigned* __restrict__ mlo, unsigned* __restrict__ mhi)
{
    const int b = blockIdx.x;
    const int tid = threadIdx.x;
    const size_t base = (size_t)b * CELLS_PER_IMG;
    for (int i = tid; i < CELLS_PER_IMG; i += 256) {
        lastGT[base + i] = -1;
        mlo[base + i] = 0u;
        mhi[base + i] = 0u;
    }
    __syncthreads();
    if (tid < 150) {
        int s = tid / 50, m = tid - s * 50;
        int lab = labels[b * MM + m];
        if (lab >= 0) {
            const float* bb = bboxes + ((size_t)b * MM + m) * 4;
            float cx = (bb[0] + bb[2]) * 0.5f * IMGF;
            float cy = (bb[1] + bb[3]) * 0.5f * IMGF;
            const int W = (s == 0) ? 52 : ((s == 1) ? 26 : 13);
            const float stride = (s == 0) ? 8.0f : ((s == 1) ? 16.0f : 32.0f);
            const int soff = (s == 0) ? 0 : ((s == 1) ? SOFF1 : SOFF2);
            int gx = (int)(cx / stride); gx = min(max(gx, 0), W - 1);
            int gy = (int)(cy / stride); gy = min(max(gy, 0), W - 1);
            int labc = min(max(lab, 0), CC - 1);
            unsigned lo = (labc < 32) ? (1u << labc) : 0u;
            unsigned hi = (labc >= 32) ? (1u << (labc - 32)) : 0u;
            for (int dy = -1; dy <= 1; ++dy) {
                for (int dx = -1; dx <= 1; ++dx) {
                    int axc = gx + dx, ayc = gy + dy;
                    if (axc >= 0 && axc < W && ayc >= 0 && ayc < W) {
                        size_t idx = base + soff + (size_t)(ayc * W + axc);
                        atomicMax(&lastGT[idx], m);     // last-write-wins == max GT idx
                        if (lo) atomicOr(&mlo[idx], lo);
                        if (hi) atomicOr(&mhi[idx], hi);
                    }
                }
            }
        }
    }
}

// K2: per-anchor loss (EXACT R2 body) + fused last-block final reduction.
__global__ __launch_bounds__(256) void v3_main(
    const float* __restrict__ cls0, const float* __restrict__ reg0, const float* __restrict__ obj0,
    const float* __restrict__ cls1, const float* __restrict__ reg1, const float* __restrict__ obj1,
    const float* __restrict__ cls2, const float* __restrict__ reg2, const float* __restrict__ obj2,
    const float* __restrict__ bboxes,
    const int* __restrict__ lastGT, const unsigned* __restrict__ mlo, const unsigned* __restrict__ mhi,
    float* __restrict__ partials, unsigned* __restrict__ counter, float* __restrict__ out)
{
    int bid = blockIdx.x;
    int s, b, chunk;
    if (bid < NBLK0)       { s = 0; b = bid / 11; chunk = bid - 11 * b; }
    else if (bid < NBLK01) { int r = bid - NBLK0; s = 1; b = r / 3; chunk = r - 3 * b; }
    else                   { s = 2; b = bid - NBLK01; chunk = 0; }

    const int   W      = (s == 0) ? 52 : ((s == 1) ? 26 : 13);
    const int   A      = W * W;
    const float stride = (s == 0) ? 8.0f : ((s == 1) ? 16.0f : 32.0f);
    const int   soff   = (s == 0) ? 0 : ((s == 1) ? SOFF1 : SOFF2);
    const float* __restrict__ cls = (s == 0) ? cls0 : ((s == 1) ? cls1 : cls2);
    const float* __restrict__ reg = (s == 0) ? reg0 : ((s == 1) ? reg1 : reg2);
    const float* __restrict__ obj = (s == 0) ? obj0 : ((s == 1) ? obj1 : obj2);

    const int tid = threadIdx.x;
    const int a = chunk * 256 + tid;
    const bool active = (a < A);
    const int ay = a / W;
    const int ax = a - ay * W;

    float obj_t = 0.f, cls_t = 0.f, box_t = 0.f, nfg = 0.f;
    if (active) {
        const size_t cidx = (size_t)b * CELLS_PER_IMG + soff + a;
        const int lg = lastGT[cidx];
        const bool fg = (lg >= 0);

        float xo = obj[(size_t)b * A + a];
        obj_t = bce_fast(xo, fg);

        if (fg) {
            nfg = 1.0f;
            unsigned lo = mlo[cidx], hi = mhi[cidx];
            float4 tbv = ((const float4*)bboxes)[(size_t)b * MM + lg];
            float t0 = tbv.x * IMGF, t1 = tbv.y * IMGF, t2 = tbv.z * IMGF, t3 = tbv.w * IMGF;

            const float* rp = reg + (size_t)b * 4 * A + a;
            float rx = rp[0], ry = rp[(size_t)A], rw = rp[(size_t)2 * A], rh = rp[(size_t)3 * A];
            float px = ((float)ax + rx) * stride;
            float py = ((float)ay + ry) * stride;
            rw = fminf(fmaxf(rw, -10.0f), 10.0f);
            rh = fminf(fmaxf(rh, -10.0f), 10.0f);
            float pw = __expf(rw) * stride;
            float ph = __expf(rh) * stride;
            float p0 = px - pw * 0.5f, p1 = py - ph * 0.5f;
            float p2 = px + pw * 0.5f, p3 = py + ph * 0.5f;
            float ix1 = fmaxf(p0, t0), iy1 = fmaxf(p1, t1);
            float ix2 = fminf(p2, t2), iy2 = fminf(p3, t3);
            float inter = fmaxf(ix2 - ix1, 0.0f) * fmaxf(iy2 - iy1, 0.0f);
            float pa = (p2 - p0) * (p3 - p1);
            float ta = (t2 - t0) * (t3 - t1);
            float iou = inter / (pa + ta - inter + 1e-7f);
            box_t = 1.0f - iou;

            const float* cp = cls + (size_t)b * CC * A + a;
            float acc = 0.0f;
            #pragma unroll
            for (int c = 0; c < CC; ++c) {
                float xv = cp[(size_t)c * A];
                bool bit = (c < 32) ? (((lo >> c) & 1u) != 0u) : (((hi >> (c - 32)) & 1u) != 0u);
                acc += focal_fast(xv, bit);
            }
            cls_t = acc;
        }
    }

    // block reduction (R2 code)
    for (int off = 32; off > 0; off >>= 1) {
        obj_t += __shfl_xor(obj_t, off);
        cls_t += __shfl_xor(cls_t, off);
        box_t += __shfl_xor(box_t, off);
        nfg   += __shfl_xor(nfg,   off);
    }
    __shared__ float s_red[4][4];
    int wid = tid >> 6, lane = tid & 63;
    if (lane == 0) {
        s_red[wid][0] = obj_t; s_red[wid][1] = cls_t;
        s_red[wid][2] = box_t; s_red[wid][3] = nfg;
    }
    __syncthreads();

    // --- the ONE delta vs R2: last-block-done fused final reduction ---
    __shared__ int s_lastf;
    if (tid == 0) {
        float o = 0.f, c = 0.f, bx = 0.f, nf = 0.f;
        for (int w = 0; w < 4; ++w) {
            o += s_red[w][0]; c += s_red[w][1]; bx += s_red[w][2]; nf += s_red[w][3];
        }
        float* p = partials + (size_t)bid * 4;
        __hip_atomic_store(&p[0], o,  __ATOMIC_RELAXED, __HIP_MEMORY_SCOPE_AGENT);
        __hip_atomic_store(&p[1], c,  __ATOMIC_RELAXED, __HIP_MEMORY_SCOPE_AGENT);
        __hip_atomic_store(&p[2], bx, __ATOMIC_RELAXED, __HIP_MEMORY_SCOPE_AGENT);
        __hip_atomic_store(&p[3], nf, __ATOMIC_RELAXED, __HIP_MEMORY_SCOPE_AGENT);
        unsigned old = __hip_atomic_fetch_add(counter, 1u, __ATOMIC_ACQ_REL, __HIP_MEMORY_SCOPE_AGENT);
        s_lastf = (old == NBLK_TOTAL - 1) ? 1 : 0;
    }
    __syncthreads();

    if (s_lastf) {
        double o[3] = {0,0,0}, c[3] = {0,0,0}, bx[3] = {0,0,0}, nf[3] = {0,0,0};
        for (int i = tid; i < NBLK_TOTAL; i += 256) {
            int sc = (i < NBLK0) ? 0 : ((i < NBLK01) ? 1 : 2);
            float* p = partials + (size_t)i * 4;
            o[sc]  += (double)__hip_atomic_load(&p[0], __ATOMIC_RELAXED, __HIP_MEMORY_SCOPE_AGENT);
            c[sc]  += (double)__hip_atomic_load(&p[1], __ATOMIC_RELAXED, __HIP_MEMORY_SCOPE_AGENT);
            bx[sc] += (double)__hip_atomic_load(&p[2], __ATOMIC_RELAXED, __HIP_MEMORY_SCOPE_AGENT);
            nf[sc] += (double)__hip_atomic_load(&p[3], __ATOMIC_RELAXED, __HIP_MEMORY_SCOPE_AGENT);
        }
        for (int ofs = 32; ofs > 0; ofs >>= 1) {
            #pragma unroll
            for (int sc = 0; sc < 3; ++sc) {
                o[sc]  += __shfl_xor(o[sc],  ofs);
                c[sc]  += __shfl_xor(c[sc],  ofs);
                bx[sc] += __shfl_xor(bx[sc], ofs);
                nf[sc] += __shfl_xor(nf[sc], ofs);
            }
        }
        __shared__ double s_dred[4][12];
        if (lane == 0) {
            #pragma unroll
            for (int sc = 0; sc < 3; ++sc) {
                s_dred[wid][sc*4+0] = o[sc];  s_dred[wid][sc*4+1] = c[sc];
                s_dred[wid][sc*4+2] = bx[sc]; s_dred[wid][sc*4+3] = nf[sc];
            }
        }
        __syncthreads();
        if (tid == 0) {
            double total = 0.0;
            #pragma unroll
            for (int sc = 0; sc < 3; ++sc) {
                double os = 0, cs = 0, bs = 0, ns = 0;
                for (int w = 0; w < 4; ++w) {
                    os += s_dred[w][sc*4+0]; cs += s_dred[w][sc*4+1];
                    bs += s_dred[w][sc*4+2]; ns += s_dred[w][sc*4+3];
                }
                double n = (ns > 1.0) ? ns : 1.0;
                total += 0.5 * (cs / (n * (double)CC)) + 7.5 * (bs / n) + 1.0 * (os / n);
            }
            out[0] = (float)(total / 3.0);
        }
    }
}

extern "C" void kernel_launch(void* const* d_in, const int* in_sizes, int n_in,
                              void* d_out, int out_size, void* d_ws, size_t ws_size,
                              hipStream_t stream) {
    const float* cls0 = (const float*)d_in[0];
    const float* reg0 = (const float*)d_in[1];
    const float* obj0 = (const float*)d_in[2];
    const float* cls1 = (const float*)d_in[3];
    const float* reg1 = (const float*)d_in[4];
    const float* obj1 = (const float*)d_in[5];
    const float* cls2 = (const float*)d_in[6];
    const float* reg2 = (const float*)d_in[7];
    const float* obj2 = (const float*)d_in[8];
    const float* bboxes = (const float*)d_in[9];
    const int*   labels = (const int*)d_in[10];

    int*      lastGT   = (int*)d_ws;
    unsigned* mlo      = (unsigned*)(lastGT + NCELLS);
    unsigned* mhi      = mlo + NCELLS;
    float*    partials = (float*)(mhi + NCELLS);
    unsigned* counter  = (unsigned*)(partials + PART_ELEMS);

    hipMemsetAsync(counter, 0, sizeof(unsigned), stream);
    v3_assign<<<BB, 256, 0, stream>>>(bboxes, labels, lastGT, mlo, mhi);
    v3_main<<<NBLK_TOTAL, 256, 0, stream>>>(cls0, reg0, obj0, cls1, reg1, obj1,
                                            cls2, reg2, obj2, bboxes,
                                            lastGT, mlo, mhi,
                                            partials, counter, (float*)d_out);
}

// Round 9
// 48.810 us; speedup vs baseline: 1.9593x; 1.9593x over previous
//
#include <hip/hip_runtime.h>
#include <math.h>

// Problem constants
#define BB 128
#define MM 50
#define CC 43
#define IMGF 416.0f

// Per-scale geometry:
//  s=0: W=52 A=2704 stride=8  chunks/b=11  blocks [0,1408)
//  s=1: W=26 A=676  stride=16 chunks/b=3   blocks [1408,1792)
//  s=2: W=13 A=169  stride=32 chunks/b=1   blocks [1792,1920)
#define NBLK0 1408
#define NBLK01 1792
#define NBLK_TOTAL 1920

#define CELLS_PER_IMG 3549   // 2704 + 676 + 169
#define SOFF1 2704
#define SOFF2 3380
#define NCELLS (BB * CELLS_PER_IMG)   // 454272

// fast, algebraically-equivalent focal:
// bce = max(x,0) - x*t + log1p(e^-|x|);  pt = exp(-bce) == (t ? sig(x) : 1-sig(x))
__device__ __forceinline__ float focal_fast(float x, bool t) {
    float e = __expf(-fabsf(x));          // v_exp
    float denom = 1.0f + e;
    float l = __logf(denom);              // v_log : log(1+e) == log1p(e^-|x|)
    float bce = fmaxf(x, 0.0f) - (t ? x : 0.0f) + l;
    float r = __builtin_amdgcn_rcpf(denom);   // v_rcp
    float sig = (x >= 0.0f) ? r : e * r;
    float pt = t ? sig : 1.0f - sig;
    float om = 1.0f - pt;
    return 0.25f * om * om * bce;
}

__device__ __forceinline__ float bce_fast(float x, bool t) {
    float e = __expf(-fabsf(x));
    float l = __logf(1.0f + e);
    return fmaxf(x, 0.0f) - (t ? x : 0.0f) + l;
}

// K1: per-image GT scatter. Block b owns image b's cells exclusively, so it
// inits them then scatters its own GTs with LDS-free global atomics.
__global__ __launch_bounds__(256) void v3_assign(
    const float* __restrict__ bboxes, const int* __restrict__ labels,
    int* __restrict__ lastGT, unsigned* __restrict__ mlo, unsigned* __restrict__ mhi)
{
    const int b = blockIdx.x;
    const int tid = threadIdx.x;
    const size_t base = (size_t)b * CELLS_PER_IMG;
    for (int i = tid; i < CELLS_PER_IMG; i += 256) {
        lastGT[base + i] = -1;
        mlo[base + i] = 0u;
        mhi[base + i] = 0u;
    }
    __syncthreads();
    if (tid < 150) {
        int s = tid / 50, m = tid - s * 50;
        int lab = labels[b * MM + m];
        if (lab >= 0) {
            const float* bb = bboxes + ((size_t)b * MM + m) * 4;
            float cx = (bb[0] + bb[2]) * 0.5f * IMGF;
            float cy = (bb[1] + bb[3]) * 0.5f * IMGF;
            const int W = (s == 0) ? 52 : ((s == 1) ? 26 : 13);
            const float stride = (s == 0) ? 8.0f : ((s == 1) ? 16.0f : 32.0f);
            const int soff = (s == 0) ? 0 : ((s == 1) ? SOFF1 : SOFF2);
            int gx = (int)(cx / stride); gx = min(max(gx, 0), W - 1);
            int gy = (int)(cy / stride); gy = min(max(gy, 0), W - 1);
            int labc = min(max(lab, 0), CC - 1);
            unsigned lo = (labc < 32) ? (1u << labc) : 0u;
            unsigned hi = (labc >= 32) ? (1u << (labc - 32)) : 0u;
            for (int dy = -1; dy <= 1; ++dy) {
                for (int dx = -1; dx <= 1; ++dx) {
                    int axc = gx + dx, ayc = gy + dy;
                    if (axc >= 0 && axc < W && ayc >= 0 && ayc < W) {
                        size_t idx = base + soff + (size_t)(ayc * W + axc);
                        atomicMax(&lastGT[idx], m);     // last-write-wins == max GT idx
                        if (lo) atomicOr(&mlo[idx], lo);
                        if (hi) atomicOr(&mhi[idx], hi);
                    }
                }
            }
        }
    }
}

// K2: per-anchor loss. Reads its own cell's assignment (coalesced), no GT scan.
__global__ __launch_bounds__(256) void v3_main(
    const float* __restrict__ cls0, const float* __restrict__ reg0, const float* __restrict__ obj0,
    const float* __restrict__ cls1, const float* __restrict__ reg1, const float* __restrict__ obj1,
    const float* __restrict__ cls2, const float* __restrict__ reg2, const float* __restrict__ obj2,
    const float* __restrict__ bboxes,
    const int* __restrict__ lastGT, const unsigned* __restrict__ mlo, const unsigned* __restrict__ mhi,
    float* __restrict__ partials)
{
    int bid = blockIdx.x;
    int s, b, chunk;
    if (bid < NBLK0)       { s = 0; b = bid / 11; chunk = bid - 11 * b; }
    else if (bid < NBLK01) { int r = bid - NBLK0; s = 1; b = r / 3; chunk = r - 3 * b; }
    else                   { s = 2; b = bid - NBLK01; chunk = 0; }

    const int   W      = (s == 0) ? 52 : ((s == 1) ? 26 : 13);
    const int   A      = W * W;
    const float stride = (s == 0) ? 8.0f : ((s == 1) ? 16.0f : 32.0f);
    const int   soff   = (s == 0) ? 0 : ((s == 1) ? SOFF1 : SOFF2);
    const float* __restrict__ cls = (s == 0) ? cls0 : ((s == 1) ? cls1 : cls2);
    const float* __restrict__ reg = (s == 0) ? reg0 : ((s == 1) ? reg1 : reg2);
    const float* __restrict__ obj = (s == 0) ? obj0 : ((s == 1) ? obj1 : obj2);

    const int tid = threadIdx.x;
    const int a = chunk * 256 + tid;
    const bool active = (a < A);
    const int ay = a / W;
    const int ax = a - ay * W;

    float obj_t = 0.f, cls_t = 0.f, box_t = 0.f, nfg = 0.f;
    if (active) {
        const size_t cidx = (size_t)b * CELLS_PER_IMG + soff + a;
        const int lg = lastGT[cidx];
        const bool fg = (lg >= 0);

        float xo = obj[(size_t)b * A + a];
        obj_t = bce_fast(xo, fg);

        if (fg) {
            nfg = 1.0f;
            unsigned lo = mlo[cidx], hi = mhi[cidx];
            float4 tbv = ((const float4*)bboxes)[(size_t)b * MM + lg];
            float t0 = tbv.x * IMGF, t1 = tbv.y * IMGF, t2 = tbv.z * IMGF, t3 = tbv.w * IMGF;

            // ---- box loss: decode + IoU with target ----
            const float* rp = reg + (size_t)b * 4 * A + a;
            float rx = rp[0], ry = rp[(size_t)A], rw = rp[(size_t)2 * A], rh = rp[(size_t)3 * A];
            float px = ((float)ax + rx) * stride;
            float py = ((float)ay + ry) * stride;
            rw = fminf(fmaxf(rw, -10.0f), 10.0f);
            rh = fminf(fmaxf(rh, -10.0f), 10.0f);
            float pw = __expf(rw) * stride;
            float ph = __expf(rh) * stride;
            float p0 = px - pw * 0.5f, p1 = py - ph * 0.5f;
            float p2 = px + pw * 0.5f, p3 = py + ph * 0.5f;
            float ix1 = fmaxf(p0, t0), iy1 = fmaxf(p1, t1);
            float ix2 = fminf(p2, t2), iy2 = fminf(p3, t3);
            float inter = fmaxf(ix2 - ix1, 0.0f) * fmaxf(iy2 - iy1, 0.0f);
            float pa = (p2 - p0) * (p3 - p1);
            float ta = (t2 - t0) * (t3 - t1);
            float iou = inter / (pa + ta - inter + 1e-7f);
            box_t = 1.0f - iou;

            // ---- cls focal loss over 43 channels (multi-hot target) ----
            const float* cp = cls + (size_t)b * CC * A + a;
            float acc = 0.0f;
            #pragma unroll
            for (int c = 0; c < CC; ++c) {
                float xv = cp[(size_t)c * A];
                bool bit = (c < 32) ? (((lo >> c) & 1u) != 0u) : (((hi >> (c - 32)) & 1u) != 0u);
                acc += focal_fast(xv, bit);
            }
            cls_t = acc;
        }
    }

    // Deterministic block reduction: wave shfl_xor then LDS across 4 waves.
    for (int off = 32; off > 0; off >>= 1) {
        obj_t += __shfl_xor(obj_t, off);
        cls_t += __shfl_xor(cls_t, off);
        box_t += __shfl_xor(box_t, off);
        nfg   += __shfl_xor(nfg,   off);
    }
    __shared__ float s_red[4][4];
    int wid = tid >> 6, lane = tid & 63;
    if (lane == 0) {
        s_red[wid][0] = obj_t; s_red[wid][1] = cls_t;
        s_red[wid][2] = box_t; s_red[wid][3] = nfg;
    }
    __syncthreads();
    if (tid == 0) {
        float o = 0.f, c = 0.f, bx = 0.f, nf = 0.f;
        for (int w = 0; w < 4; ++w) {
            o += s_red[w][0]; c += s_red[w][1]; bx += s_red[w][2]; nf += s_red[w][3];
        }
        float* p = partials + (size_t)bid * 4;
        p[0] = o; p[1] = c; p[2] = bx; p[3] = nf;
    }
}

__global__ __launch_bounds__(256) void v3_final(const float* __restrict__ partials,
                                                float* __restrict__ out)
{
    const int tid = threadIdx.x;
    double o[3] = {0, 0, 0}, c[3] = {0, 0, 0}, bx[3] = {0, 0, 0}, nf[3] = {0, 0, 0};
    for (int i = tid; i < NBLK_TOTAL; i += 256) {
        int s = (i < NBLK0) ? 0 : ((i < NBLK01) ? 1 : 2);
        const float* p = partials + (size_t)i * 4;
        o[s]  += (double)p[0];
        c[s]  += (double)p[1];
        bx[s] += (double)p[2];
        nf[s] += (double)p[3];
    }
    for (int off = 32; off > 0; off >>= 1) {
        for (int s = 0; s < 3; ++s) {
            o[s]  += __shfl_xor(o[s],  off);
            c[s]  += __shfl_xor(c[s],  off);
            bx[s] += __shfl_xor(bx[s], off);
            nf[s] += __shfl_xor(nf[s], off);
        }
    }
    __shared__ double s_red[4][12];
    int wid = tid >> 6, lane = tid & 63;
    if (lane == 0) {
        for (int s = 0; s < 3; ++s) {
            s_red[wid][s * 4 + 0] = o[s];
            s_red[wid][s * 4 + 1] = c[s];
            s_red[wid][s * 4 + 2] = bx[s];
            s_red[wid][s * 4 + 3] = nf[s];
        }
    }
    __syncthreads();
    if (tid == 0) {
        double total = 0.0;
        for (int s = 0; s < 3; ++s) {
            double os = 0, cs = 0, bs = 0, ns = 0;
            for (int w = 0; w < 4; ++w) {
                os += s_red[w][s * 4 + 0];
                cs += s_red[w][s * 4 + 1];
                bs += s_red[w][s * 4 + 2];
                ns += s_red[w][s * 4 + 3];
            }
            double n = (ns > 1.0) ? ns : 1.0;
            total += 0.5 * (cs / (n * (double)CC)) + 7.5 * (bs / n) + 1.0 * (os / n);
        }
        out[0] = (float)(total / 3.0);
    }
}

extern "C" void kernel_launch(void* const* d_in, const int* in_sizes, int n_in,
                              void* d_out, int out_size, void* d_ws, size_t ws_size,
                              hipStream_t stream) {
    const float* cls0 = (const float*)d_in[0];
    const float* reg0 = (const float*)d_in[1];
    const float* obj0 = (const float*)d_in[2];
    const float* cls1 = (const float*)d_in[3];
    const float* reg1 = (const float*)d_in[4];
    const float* obj1 = (const float*)d_in[5];
    const float* cls2 = (const float*)d_in[6];
    const float* reg2 = (const float*)d_in[7];
    const float* obj2 = (const float*)d_in[8];
    const float* bboxes = (const float*)d_in[9];
    const int*   labels = (const int*)d_in[10];

    // workspace layout (all 4B-aligned):
    //   int      lastGT[NCELLS]   1.82 MB
    //   unsigned mlo[NCELLS]      1.82 MB
    //   unsigned mhi[NCELLS]      1.82 MB
    //   float    partials[1920*4] 30 KB
    int*      lastGT   = (int*)d_ws;
    unsigned* mlo      = (unsigned*)(lastGT + NCELLS);
    unsigned* mhi      = mlo + NCELLS;
    float*    partials = (float*)(mhi + NCELLS);

    v3_assign<<<BB, 256, 0, stream>>>(bboxes, labels, lastGT, mlo, mhi);
    v3_main<<<NBLK_TOTAL, 256, 0, stream>>>(cls0, reg0, obj0, cls1, reg1, obj1,
                                            cls2, reg2, obj2, bboxes,
                                            lastGT, mlo, mhi, partials);
    v3_final<<<1, 256, 0, stream>>>(partials, (float*)d_out);
}

// Round 10
// 33.756 us; speedup vs baseline: 2.8332x; 1.4460x over previous
//
#include <hip/hip_runtime.h>
#include <math.h>

// Problem constants
#define BB 128
#define MM 50
#define CC 43
#define IMGF 416.0f

// Per-scale geometry:
//  s=0: W=52 A=2704 stride=8  chunks/b=11  blocks [0,1408)
//  s=1: W=26 A=676  stride=16 chunks/b=3   blocks [1408,1792)
//  s=2: W=13 A=169  stride=32 chunks/b=1   blocks [1792,1920)
#define NBLK0 1408
#define NBLK01 1792
#define NBLK_TOTAL 1920

// workspace: partials[1920*4] floats
// fast, algebraically-equivalent focal:
// bce = max(x,0) - x*t + log1p(e^-|x|);  pt = exp(-bce) == (t ? sig(x) : 1-sig(x))
__device__ __forceinline__ float focal_fast(float x, bool t) {
    float e = __expf(-fabsf(x));          // v_exp
    float denom = 1.0f + e;
    float l = __logf(denom);              // v_log : log(1+e) == log1p(e^-|x|)
    float bce = fmaxf(x, 0.0f) - (t ? x : 0.0f) + l;
    float r = __builtin_amdgcn_rcpf(denom);   // v_rcp
    float sig = (x >= 0.0f) ? r : e * r;
    float pt = t ? sig : 1.0f - sig;
    float om = 1.0f - pt;
    return 0.25f * om * om * bce;
}

__device__ __forceinline__ float bce_fast(float x, bool t) {
    float e = __expf(-fabsf(x));
    float l = __logf(1.0f + e);
    return fmaxf(x, 0.0f) - (t ? x : 0.0f) + l;
}

// Single main kernel: in-block LDS assignment (no global scatter state, no
// assign kernel) + R2/R9's proven per-anchor loss body + plain partials store.
// NOTE (session rule, R8/R9 A/B): NO agent-scope ordered atomics anywhere —
// the fused last-block tail regressed 49->96 us. Final reduce stays separate.
__global__ __launch_bounds__(256) void v3_main(
    const float* __restrict__ cls0, const float* __restrict__ reg0, const float* __restrict__ obj0,
    const float* __restrict__ cls1, const float* __restrict__ reg1, const float* __restrict__ obj1,
    const float* __restrict__ cls2, const float* __restrict__ reg2, const float* __restrict__ obj2,
    const float* __restrict__ bboxes, const int* __restrict__ labels,
    float* __restrict__ partials)
{
    const int bid = blockIdx.x;
    int s, b, chunk;
    if (bid < NBLK0)       { s = 0; b = bid / 11; chunk = bid - 11 * b; }
    else if (bid < NBLK01) { int r = bid - NBLK0; s = 1; b = r / 3; chunk = r - 3 * b; }
    else                   { s = 2; b = bid - NBLK01; chunk = 0; }

    int W, A; float strd, inv_strd;
    const float *cls, *reg, *obj;
    if (s == 0)      { W = 52; A = 2704; strd = 8.f;  inv_strd = 0.125f;   cls = cls0; reg = reg0; obj = obj0; }
    else if (s == 1) { W = 26; A = 676;  strd = 16.f; inv_strd = 0.0625f;  cls = cls1; reg = reg1; obj = obj1; }
    else             { W = 13; A = 169;  strd = 32.f; inv_strd = 0.03125f; cls = cls2; reg = reg2; obj = obj2; }

    const int tid = threadIdx.x;
    const int lane = tid & 63, wid = tid >> 6;
    const int a_lo = chunk << 8;
    const int a_hi = min(a_lo + 255, A - 1);
    const int a = a_lo + tid;
    const bool active = (a < A);

    // ---- LDS: GT staging + per-cell GT-incidence masks (block-local) ----
    __shared__ int    s_lab[MM];
    __shared__ float4 s_boxv[MM];
    __shared__ unsigned s_glo[256], s_ghi[256];

    // Phase 1a: zero cell masks; 50 lanes stage GT data + centers
    s_glo[tid] = 0u; s_ghi[tid] = 0u;
    int gx = -1, gy = -1, my_lab = -1;
    if (tid < MM) {
        my_lab = labels[b * MM + tid];
        float4 bb = ((const float4*)bboxes)[b * MM + tid];
        float4 pb = make_float4(bb.x * IMGF, bb.y * IMGF, bb.z * IMGF, bb.w * IMGF);
        s_boxv[tid] = pb;
        s_lab[tid] = min(max(my_lab, 0), CC - 1);
        float cx = (pb.x + pb.z) * 0.5f;
        float cy = (pb.y + pb.w) * 0.5f;
        gx = (int)(cx * inv_strd); gx = min(max(gx, 0), W - 1);
        gy = (int)(cy * inv_strd); gy = min(max(gy, 0), W - 1);
    }
    __syncthreads();

    // Phase 1b: idempotent scatter of GT bits into this block's cell window
    if (tid < MM && my_lab >= 0) {
        unsigned bit = 1u << (tid & 31);
        bool is_hi = (tid >= 32);
        #pragma unroll
        for (int dy = -1; dy <= 1; ++dy) {
            int yy = gy + dy;
            if ((unsigned)yy < (unsigned)W) {
                #pragma unroll
                for (int dx = -1; dx <= 1; ++dx) {
                    int xx = gx + dx;
                    if ((unsigned)xx < (unsigned)W) {
                        int ac = yy * W + xx;
                        if (ac >= a_lo && ac <= a_hi) {
                            if (is_hi) atomicOr(&s_ghi[ac - a_lo], bit);
                            else       atomicOr(&s_glo[ac - a_lo], bit);
                        }
                    }
                }
            }
        }
    }
    __syncthreads();

    // ---- Phase 2: per-anchor losses (R2/R9 proven body) ----
    int ay;
    if (s == 0) ay = a / 52; else if (s == 1) ay = a / 26; else ay = a / 13;
    const int ax = a - ay * W;

    const unsigned glo = s_glo[tid], ghi = s_ghi[tid];
    const bool fg = (glo | ghi) != 0u;   // inactive cells never receive bits

    float obj_t = 0.f, cls_t = 0.f, box_t = 0.f, nfg = 0.f;
    if (active) {
        float xo = obj[(size_t)b * A + a];
        obj_t = bce_fast(xo, fg);
    }
    if (fg) {
        nfg = 1.0f;
        // class multi-hot = union of labels over covering GTs
        unsigned lo = 0u, hi = 0u;
        unsigned t = glo;
        while (t) {
            int m = __builtin_ctz(t); t &= t - 1;
            int lc = s_lab[m];
            if (lc < 32) lo |= 1u << lc; else hi |= 1u << (lc - 32);
        }
        t = ghi;
        while (t) {
            int m = 32 + __builtin_ctz(t); t &= t - 1;
            int lc = s_lab[m];
            if (lc < 32) lo |= 1u << lc; else hi |= 1u << (lc - 32);
        }
        // last-write-wins box target = max set GT index
        int mstar = ghi ? (32 + 31 - __builtin_clz(ghi)) : (31 - __builtin_clz(glo));
        float4 tb = s_boxv[mstar];

        // ---- box loss: decode + IoU with target ----
        const float* rp = reg + (size_t)b * 4 * A + a;
        float rx = rp[0], ry = rp[(size_t)A], rw = rp[(size_t)2 * A], rh = rp[(size_t)3 * A];
        float px = ((float)ax + rx) * strd;
        float py = ((float)ay + ry) * strd;
        rw = fminf(fmaxf(rw, -10.0f), 10.0f);
        rh = fminf(fmaxf(rh, -10.0f), 10.0f);
        float pw = __expf(rw) * strd;
        float ph = __expf(rh) * strd;
        float p0 = px - pw * 0.5f, p1 = py - ph * 0.5f;
        float p2 = px + pw * 0.5f, p3 = py + ph * 0.5f;
        float ix1 = fmaxf(p0, tb.x), iy1 = fmaxf(p1, tb.y);
        float ix2 = fminf(p2, tb.z), iy2 = fminf(p3, tb.w);
        float inter = fmaxf(ix2 - ix1, 0.0f) * fmaxf(iy2 - iy1, 0.0f);
        float pa = (p2 - p0) * (p3 - p1);
        float ta = (tb.z - tb.x) * (tb.w - tb.y);
        float iou = inter / (pa + ta - inter + 1e-7f);
        box_t = 1.0f - iou;

        // ---- cls focal loss over 43 channels (multi-hot target) ----
        const float* cp = cls + (size_t)b * CC * A + a;
        float acc = 0.0f;
        #pragma unroll
        for (int c = 0; c < CC; ++c) {
            float xv = cp[(size_t)c * A];
            bool bit = (c < 32) ? (((lo >> c) & 1u) != 0u) : (((hi >> (c - 32)) & 1u) != 0u);
            acc += focal_fast(xv, bit);
        }
        cls_t = acc;
    }

    // Deterministic block reduction: wave shfl_xor then LDS across 4 waves.
    for (int off = 32; off > 0; off >>= 1) {
        obj_t += __shfl_xor(obj_t, off);
        cls_t += __shfl_xor(cls_t, off);
        box_t += __shfl_xor(box_t, off);
        nfg   += __shfl_xor(nfg,   off);
    }
    __shared__ float s_red[4][4];
    if (lane == 0) {
        s_red[wid][0] = obj_t; s_red[wid][1] = cls_t;
        s_red[wid][2] = box_t; s_red[wid][3] = nfg;
    }
    __syncthreads();
    if (tid == 0) {
        float o = 0.f, c = 0.f, bx = 0.f, nf = 0.f;
        for (int w = 0; w < 4; ++w) {
            o += s_red[w][0]; c += s_red[w][1]; bx += s_red[w][2]; nf += s_red[w][3];
        }
        float* p = partials + (size_t)bid * 4;
        p[0] = o; p[1] = c; p[2] = bx; p[3] = nf;
    }
}

__global__ __launch_bounds__(256) void v3_final(const float* __restrict__ partials,
                                                float* __restrict__ out)
{
    const int tid = threadIdx.x;
    double o[3] = {0, 0, 0}, c[3] = {0, 0, 0}, bx[3] = {0, 0, 0}, nf[3] = {0, 0, 0};
    for (int i = tid; i < NBLK_TOTAL; i += 256) {
        int s = (i < NBLK0) ? 0 : ((i < NBLK01) ? 1 : 2);
        const float* p = partials + (size_t)i * 4;
        o[s]  += (double)p[0];
        c[s]  += (double)p[1];
        bx[s] += (double)p[2];
        nf[s] += (double)p[3];
    }
    for (int off = 32; off > 0; off >>= 1) {
        for (int s = 0; s < 3; ++s) {
            o[s]  += __shfl_xor(o[s],  off);
            c[s]  += __shfl_xor(c[s],  off);
            bx[s] += __shfl_xor(bx[s], off);
            nf[s] += __shfl_xor(nf[s], off);
        }
    }
    __shared__ double s_red[4][12];
    int wid = tid >> 6, lane = tid & 63;
    if (lane == 0) {
        for (int s = 0; s < 3; ++s) {
            s_red[wid][s * 4 + 0] = o[s];
            s_red[wid][s * 4 + 1] = c[s];
            s_red[wid][s * 4 + 2] = bx[s];
            s_red[wid][s * 4 + 3] = nf[s];
        }
    }
    __syncthreads();
    if (tid == 0) {
        double total = 0.0;
        for (int s = 0; s < 3; ++s) {
            double os = 0, cs = 0, bs = 0, ns = 0;
            for (int w = 0; w < 4; ++w) {
                os += s_red[w][s * 4 + 0];
                cs += s_red[w][s * 4 + 1];
                bs += s_red[w][s * 4 + 2];
                ns += s_red[w][s * 4 + 3];
            }
            double n = (ns > 1.0) ? ns : 1.0;
            total += 0.5 * (cs / (n * (double)CC)) + 7.5 * (bs / n) + 1.0 * (os / n);
        }
        out[0] = (float)(total / 3.0);
    }
}

extern "C" void kernel_launch(void* const* d_in, const int* in_sizes, int n_in,
                              void* d_out, int out_size, void* d_ws, size_t ws_size,
                              hipStream_t stream) {
    const float* cls0 = (const float*)d_in[0];
    const float* reg0 = (const float*)d_in[1];
    const float* obj0 = (const float*)d_in[2];
    const float* cls1 = (const float*)d_in[3];
    const float* reg1 = (const float*)d_in[4];
    const float* obj1 = (const float*)d_in[5];
    const float* cls2 = (const float*)d_in[6];
    const float* reg2 = (const float*)d_in[7];
    const float* obj2 = (const float*)d_in[8];
    const float* bboxes = (const float*)d_in[9];
    const int*   labels = (const int*)d_in[10];

    float* partials = (float*)d_ws;   // 1920*4 floats = 30720 B

    v3_main<<<NBLK_TOTAL, 256, 0, stream>>>(cls0, reg0, obj0, cls1, reg1, obj1,
                                            cls2, reg2, obj2, bboxes, labels,
                                            partials);
    v3_final<<<1, 256, 0, stream>>>(partials, (float*)d_out);
}